// Round 4
// baseline (597.875 us; speedup 1.0000x reference)
//
#include <hip/hip_runtime.h>
#include <hip/hip_bf16.h>

#define B_ 4
#define N_ 2048
#define F_ 256
#define H_ 8
#define O_ 256

// log2(e)/16 folded into Q so softmax can use exp2f (exact softmax, monotone map)
#define SCALE_QK 0.09016844005556021f

typedef __attribute__((ext_vector_type(8))) short short8;
typedef __attribute__((ext_vector_type(4))) float f32x4;

static __device__ __forceinline__ float bf2f(short u) {
    unsigned int x = ((unsigned int)(unsigned short)u) << 16;
    return __builtin_bit_cast(float, x);
}
static __device__ __forceinline__ short f2bf(float f) {
    unsigned int x = __builtin_bit_cast(unsigned int, f);
    unsigned int lsb = (x >> 16) & 1u;
    x += 0x7fffu + lsb;
    return (short)(x >> 16);
}

// ---- input normalizer: sniff whether src is f32 or bf16, emit bf16 ----
// (Round 3 evidence: inputs ARE f32 — sniff retained as zero-cost insurance.)
__global__ __launch_bounds__(256) void cvt_kernel(const void* __restrict__ src,
                                                  const short* __restrict__ sniff_src,
                                                  short* __restrict__ dst, int n) {
    bool isf32 = false;
#pragma unroll 4
    for (int i = 0; i < 256; i++) {
        float v = bf2f(sniff_src[i]);
        if (!(__builtin_fabsf(v) <= 1e6f)) isf32 = true;   // catches NaN too
    }
    int tid = threadIdx.x;
    if (n >= 2048) {
        size_t base = ((size_t)blockIdx.x * 256 + tid) * 8;
        if (isf32) {
            const float* s = (const float*)src;
#pragma unroll
            for (int j = 0; j < 8; j++) dst[base + j] = f2bf(s[base + j]);
        } else {
            *(short8*)&dst[base] = *(const short8*)&((const short*)src)[base];
        }
    } else {
        int i = blockIdx.x * 256 + tid;
        if (i < n) dst[i] = isf32 ? f2bf(((const float*)src)[i]) : ((const short*)src)[i];
    }
}

// ---------------- generic bf16 transpose: dst[c][r] = src[r][c], batched ----
__global__ __launch_bounds__(256) void transpose_k(const short* __restrict__ src,
                                                   short* __restrict__ dst,
                                                   int R, int C) {
    __shared__ short tile[32][33];
    size_t bofs = (size_t)blockIdx.z * R * C;
    src += bofs; dst += bofs;
    int tx = threadIdx.x, ty = threadIdx.y;           // 32 x 8
    int c0 = blockIdx.x * 32, r0 = blockIdx.y * 32;
#pragma unroll
    for (int j = 0; j < 4; j++) {
        int r = r0 + ty + j * 8;
        tile[ty + j * 8][tx] = src[(size_t)r * C + c0 + tx];
    }
    __syncthreads();
#pragma unroll
    for (int j = 0; j < 4; j++) {
        int c = c0 + ty + j * 8;
        dst[(size_t)c * R + r0 + tx] = tile[tx][ty + j * 8];
    }
}

// ---- 64-row MFMA GEMM tile, B^T input: C[m][n] = sum_k A[m][k]*Bt[n][k]
// NCT = number of 16-wide output column tiles. OUT_F32: f32 vs bf16 C-store.
template <int NCT, bool OUT_F32>
__device__ __forceinline__ void gemm64_bt(const short* __restrict__ A, int lda,
                                          const short* __restrict__ Bt, int ldb,
                                          void* __restrict__ Cp, int ldc,
                                          int K, const short* __restrict__ bias) {
    __shared__ short sA[64][72];        // +8 pad: breaks pow2 bank stride
    __shared__ short sB[NCT * 16][72];
    int tid = threadIdx.x;
    int w = tid >> 6, l = tid & 63, lq = l & 15, quad = l >> 4;
    f32x4 acc[NCT];
#pragma unroll
    for (int i = 0; i < NCT; i++) acc[i] = (f32x4)(0.f);

    for (int kb = 0; kb < K; kb += 64) {
        __syncthreads();   // protect previous iter's reads
#pragma unroll
        for (int i = 0; i < 2; i++) {
            int idx = tid + i * 256; int r = idx >> 3, c = (idx & 7) * 8;
            *(short8*)&sA[r][c] = *(const short8*)&A[(size_t)r * lda + kb + c];
        }
#pragma unroll
        for (int i = 0; i < NCT / 2; i++) {
            int idx = tid + i * 256; int r = idx >> 3, c = (idx & 7) * 8;
            *(short8*)&sB[r][c] = *(const short8*)&Bt[(size_t)r * ldb + kb + c];
        }
        __syncthreads();
#pragma unroll
        for (int kk = 0; kk < 2; kk++) {
            short8 af = *(const short8*)&sA[w * 16 + lq][kk * 32 + quad * 8];
#pragma unroll
            for (int ct = 0; ct < NCT; ct++) {
                short8 bf = *(const short8*)&sB[ct * 16 + lq][kk * 32 + quad * 8];
                acc[ct] = __builtin_amdgcn_mfma_f32_16x16x32_bf16(af, bf, acc[ct], 0, 0, 0);
            }
        }
    }
    // epilogue: C/D layout row=(quad*4+r), col=(ct*16+lq)
#pragma unroll
    for (int ct = 0; ct < NCT; ct++) {
        int col = ct * 16 + lq;
        float bv = bias ? bf2f(bias[col]) : 0.f;
#pragma unroll
        for (int r = 0; r < 4; r++) {
            int row = w * 16 + quad * 4 + r;
            float v = acc[ct][r] + bv;
            if (OUT_F32) ((float*)Cp)[(size_t)row * ldc + col] = v;
            else         ((short*)Cp)[(size_t)row * ldc + col] = f2bf(v);
        }
    }
}

// out[m][o] = sum_k msgs[m][k] * Wout[k][o] + bias[o]; grid (128, 2); f32 out
__global__ __launch_bounds__(256) void out_kernel(const short* __restrict__ msgs,
                                                  const short* __restrict__ WoutT,
                                                  const short* __restrict__ bias,
                                                  float* __restrict__ out) {
    int mt = blockIdx.x, nt = blockIdx.y;
    gemm64_bt<8, true>(msgs + (size_t)mt * 64 * (H_ * F_), H_ * F_,
                       WoutT + (size_t)nt * 128 * (H_ * F_), H_ * F_,
                       out + (size_t)mt * 64 * O_ + nt * 128, O_,
                       H_ * F_, bias + nt * 128);
}

// -------- fused flash attention: per (bh, 64-query tile); BN=64 keys/iter.
// Phase 0 computes Q = (X qtile @ Wh) * SCALE_QK in-block (no xw buffer).
__global__ __launch_bounds__(256) void attn_kernel(const short* __restrict__ X,
                                                   const short* __restrict__ WhT,
                                                   const short* __restrict__ XT,
                                                   short* __restrict__ msgs) {
    __shared__ short kv[64][264];     // [key][feat]  (+8 pad); also Q staging
    __shared__ short kvT[256][72];    // [feat][key]  (+8 pad); also WhT staging
    __shared__ short pl[4][16][72];   // per-wave P staging [qrow][key]

    int qt = blockIdx.x, bh = blockIdx.y, b = bh >> 3, h = bh & 7;
    int tid = threadIdx.x, w = tid >> 6, l = tid & 63, lq = l & 15, quad = l >> 4;
    int q0 = qt * 64;

    const short* Xb  = X  + (size_t)b * N_ * F_;
    const short* XTb = XT + (size_t)b * F_ * N_;
    const short* Whh = WhT + (size_t)h * F_ * F_;

    // ---------- phase 0: Q-projection ----------
#pragma unroll
    for (int i = 0; i < 8; i++) {               // stage X q-tile into kv
        int idx = tid + i * 256; int r = idx >> 5, c = (idx & 31) * 8;
        *(short8*)&kv[r][c] = *(const short8*)&Xb[(size_t)(q0 + r) * F_ + c];
    }
    f32x4 oacc[16];
#pragma unroll
    for (int i = 0; i < 16; i++) oacc[i] = (f32x4)(0.f);

    for (int kb = 0; kb < 4; kb++) {
        __syncthreads();                        // prev kvT reads done (kb>0)
#pragma unroll
        for (int i = 0; i < 8; i++) {           // stage WhT[h] k-chunk into kvT
            int idx = tid + i * 256; int f = idx >> 3, c = (idx & 7) * 8;
            *(short8*)&kvT[f][c] = *(const short8*)&Whh[(size_t)f * F_ + kb * 64 + c];
        }
        __syncthreads();                        // kv (kb==0) + kvT visible
#pragma unroll
        for (int kk = 0; kk < 2; kk++) {
            short8 af = *(const short8*)&kv[w * 16 + lq][kb * 64 + kk * 32 + quad * 8];
#pragma unroll
            for (int ct = 0; ct < 16; ct++) {
                short8 bf = *(const short8*)&kvT[ct * 16 + lq][kk * 32 + quad * 8];
                oacc[ct] = __builtin_amdgcn_mfma_f32_16x16x32_bf16(af, bf, oacc[ct], 0, 0, 0);
            }
        }
    }
    __syncthreads();                            // all kv reads done before overwrite
    // write scaled Q (bf16) into kv: C-layout row=(w*16+quad*4+r), col=(ct*16+lq)
#pragma unroll
    for (int ct = 0; ct < 16; ct++) {
        int col = ct * 16 + lq;
#pragma unroll
        for (int r = 0; r < 4; r++)
            kv[w * 16 + quad * 4 + r][col] = f2bf(oacc[ct][r] * SCALE_QK);
    }
    __syncthreads();
    // Q fragments (A-layout) held in registers for the whole kernel
    short8 aq[8];
#pragma unroll
    for (int kk = 0; kk < 8; kk++)
        aq[kk] = *(const short8*)&kv[w * 16 + lq][kk * 32 + quad * 8];

    // ---------- phase 1: flash attention over key tiles ----------
#pragma unroll
    for (int i = 0; i < 16; i++) oacc[i] = (f32x4)(0.f);
    float mrow[4], lrow[4];
#pragma unroll
    for (int r = 0; r < 4; r++) { mrow[r] = -INFINITY; lrow[r] = 0.f; }

    for (int kt = 0; kt < N_ / 64; kt++) {
        __syncthreads();   // previous iter (and aq reads) done before restaging
#pragma unroll
        for (int i = 0; i < 8; i++) {           // stage kv[key][feat]
            int idx = tid + i * 256; int r = idx >> 5, c = (idx & 31) * 8;
            *(short8*)&kv[r][c] = *(const short8*)&Xb[(size_t)(kt * 64 + r) * F_ + c];
        }
#pragma unroll
        for (int i = 0; i < 8; i++) {           // stage kvT[feat][key] from XT
            int idx = tid + i * 256; int f = idx >> 3, c = (idx & 7) * 8;
            *(short8*)&kvT[f][c] = *(const short8*)&XTb[(size_t)f * N_ + kt * 64 + c];
        }
        __syncthreads();

        // S = Q @ K^T  (contraction over feat; kv gives B^T[n=key][k=feat])
        f32x4 sacc[4];
#pragma unroll
        for (int ct = 0; ct < 4; ct++) sacc[ct] = (f32x4)(0.f);
#pragma unroll
        for (int kk = 0; kk < 8; kk++) {
#pragma unroll
            for (int ct = 0; ct < 4; ct++) {
                short8 bf = *(const short8*)&kv[ct * 16 + lq][kk * 32 + quad * 8];
                sacc[ct] = __builtin_amdgcn_mfma_f32_16x16x32_bf16(aq[kk], bf, sacc[ct], 0, 0, 0);
            }
        }

        // online softmax; state rows (quad*4+r) match oacc rows — no broadcast
        float p[4][4], alpha[4];
#pragma unroll
        for (int r = 0; r < 4; r++) {
            float mx = sacc[0][r];
#pragma unroll
            for (int ct = 1; ct < 4; ct++) mx = fmaxf(mx, sacc[ct][r]);
            mx = fmaxf(mx, __shfl_xor(mx, 1));
            mx = fmaxf(mx, __shfl_xor(mx, 2));
            mx = fmaxf(mx, __shfl_xor(mx, 4));
            mx = fmaxf(mx, __shfl_xor(mx, 8));
            float mn = fmaxf(mrow[r], mx);
            alpha[r] = exp2f(mrow[r] - mn);
            mrow[r] = mn;
            float s = 0.f;
#pragma unroll
            for (int ct = 0; ct < 4; ct++) {
                float pv = exp2f(sacc[ct][r] - mn);
                p[ct][r] = pv; s += pv;
            }
            s += __shfl_xor(s, 1); s += __shfl_xor(s, 2);
            s += __shfl_xor(s, 4); s += __shfl_xor(s, 8);
            lrow[r] = lrow[r] * alpha[r] + s;
        }
#pragma unroll
        for (int ct = 0; ct < 16; ct++)
#pragma unroll
            for (int r = 0; r < 4; r++) oacc[ct][r] *= alpha[r];

        // P: C-layout -> LDS [qrow][key] -> A-layout frags
#pragma unroll
        for (int ct = 0; ct < 4; ct++)
#pragma unroll
            for (int r = 0; r < 4; r++)
                pl[w][quad * 4 + r][ct * 16 + lq] = f2bf(p[ct][r]);
        __syncthreads();   // guarantees pl write->read ordering (and kv/kvT reads ok)

        short8 pa0 = *(const short8*)&pl[w][lq][quad * 8];
        short8 pa1 = *(const short8*)&pl[w][lq][32 + quad * 8];
        // O += P @ V  (contraction over key; kvT gives B^T[n=feat][k=key])
#pragma unroll
        for (int ct = 0; ct < 16; ct++) {
            short8 b0 = *(const short8*)&kvT[ct * 16 + lq][quad * 8];
            oacc[ct] = __builtin_amdgcn_mfma_f32_16x16x32_bf16(pa0, b0, oacc[ct], 0, 0, 0);
            short8 b1 = *(const short8*)&kvT[ct * 16 + lq][32 + quad * 8];
            oacc[ct] = __builtin_amdgcn_mfma_f32_16x16x32_bf16(pa1, b1, oacc[ct], 0, 0, 0);
        }
    }

    // epilogue: normalize and write msgs[b*N + n][h*F + f]
    float inv[4];
#pragma unroll
    for (int r = 0; r < 4; r++) inv[r] = 1.f / lrow[r];
    short* Mout = msgs + ((size_t)(b * N_ + q0 + w * 16)) * (H_ * F_) + h * F_;
#pragma unroll
    for (int ct = 0; ct < 16; ct++) {
        int col = ct * 16 + lq;
#pragma unroll
        for (int r = 0; r < 4; r++) {
            int row = quad * 4 + r;
            Mout[(size_t)row * (H_ * F_) + col] = f2bf(oacc[ct][r] * inv[r]);
        }
    }
}

extern "C" void kernel_launch(void* const* d_in, const int* in_sizes, int n_in,
                              void* d_out, int out_size, void* d_ws, size_t ws_size,
                              hipStream_t stream) {
    const void* nodes_raw = d_in[0];   // [4,2048,256]  f32 (sniffed)
    const void* Wh_raw    = d_in[1];   // [8,256,256]
    const void* Wout_raw  = d_in[2];   // [2048,256]
    const void* bias_raw  = d_in[3];   // [256]
    float* out = (float*)d_out;        // [4,2048,256] f32  <-- round-3 fix

    char* ws = (char*)d_ws;
    short* msgs   = (short*)(ws);                   // [8192][2048] bf16 = 32 MB
    short* WhT    = (short*)(ws + 33554432);        // [8][256][256]       1 MB
    short* WoutT  = (short*)(ws + 34603008);        // [256][2048]         1 MB
    short* XT     = (short*)(ws + 35651584);        // [4][256][2048]      4 MB
    short* Xbf    = (short*)(ws + 39845888);        // [4][2048][256]      4 MB
    short* Whbf   = (short*)(ws + 44040192);        // [8][256][256]       1 MB
    short* Woutbf = (short*)(ws + 45088768);        // [2048][256]         1 MB
    short* biasbf = (short*)(ws + 46137344);        // [256]             0.5 KB

    const short* sniff = (const short*)nodes_raw;
    hipLaunchKernelGGL(cvt_kernel, dim3(2097152 / 2048), dim3(256), 0, stream,
                       nodes_raw, sniff, Xbf, 2097152);
    hipLaunchKernelGGL(cvt_kernel, dim3(524288 / 2048), dim3(256), 0, stream,
                       Wh_raw, sniff, Whbf, 524288);
    hipLaunchKernelGGL(cvt_kernel, dim3(524288 / 2048), dim3(256), 0, stream,
                       Wout_raw, sniff, Woutbf, 524288);
    hipLaunchKernelGGL(cvt_kernel, dim3(1), dim3(256), 0, stream,
                       bias_raw, sniff, biasbf, 256);

    dim3 tblk(32, 8, 1);
    hipLaunchKernelGGL(transpose_k, dim3(8, 8, 8),  tblk, 0, stream, Whbf,   WhT,   256,  256);
    hipLaunchKernelGGL(transpose_k, dim3(8, 64, 1), tblk, 0, stream, Woutbf, WoutT, 2048, 256);
    hipLaunchKernelGGL(transpose_k, dim3(8, 64, 4), tblk, 0, stream, Xbf,    XT,    2048, 256);

    hipLaunchKernelGGL(attn_kernel, dim3(32, 32), dim3(256), 0, stream, Xbf, WhT, XT, msgs);
    hipLaunchKernelGGL(out_kernel,  dim3(128, 2), dim3(256), 0, stream, msgs, WoutT, biasbf, out);
}